// Round 1
// 135.789 us; speedup vs baseline: 1.0164x; 1.0164x over previous
//
#include <hip/hip_runtime.h>
#include <math.h>

// KTVLoss: inputs out_l, out_r, input_i : (8,3,512,512) fp32. Output: 1 fp32 scalar.
//
// Sx = 10x10 box sum of |dI/dh| (502x503), Sy = box sum of |dI/dw| (503x502).
// Reference pairs them by FLAT index: Sx(i,j) with Sy(i,i+j) if i+j<502 else
// Sy(i+1,i+j-502). ratio = (SxL+SyL+SxR+SyR)/(SxI+SyI+1e-4), mean over 24*502*503.
// grad part (fp32): mean|GxL+GxR-GxI| + mean|GyL+GyR-GyI| over 24*511*512 each.
// norm part carries 1e-4 weight -> packed f16 (abs err ~1e-5; validated R4-R9).
//
// R11 (this round): 2-row SUPERSTEP pipeline, ONE barrier per 2 rows (35 -> 19
// barriers). Evidence: VALUBusy 36%, HBM 12%, ~3800 cyc/step vs ~200 cyc issue
// => barrier/latency stall dominates; occupancy is quantized at 2 blocks/CU
// (8-wave blocks; 3 blocks needs <=85 VGPR) so the only lever is stall/wave.
//   phase1(T): issue hist/bnd ds_reads (for rows 2T-2,2T-1) -> SCAN rows
//              2T,2T+1 (4 independent DPP scan chains hide the ds latency)
//              -> PATCH+RING rows 2T-2,2T-1 (bnd synced by barrier T-1),
//              snapshot Sx rows 2T-12,2T-11, write Sy rows 2T-11,2T-10
//   BARRIER (lgkmcnt-only; globals stay in flight)
//   phase2(T): RATIO rows 2T-12,2T-11 (Sy rows all >=1 phase old)
// Pipeline state (+16 VGPR) paid for by moving the 10-deep h-rings (20 VGPR)
// to LDS (thread-private slots, static offsets, 2-way bank alias = free).
// bnd double-buffered by superstep parity; syring depth 4 -> 8 (wave-skew
// window spans rows a-14..a-8; max skew = one phase pair, barrier-bounded).
//
// VGPR cap law (R4-R7): cap = 256/min_waves; (512,2) -> 128. Watch for spill.

namespace {

constexpr int H = 512, W = 512;
constexpr int CX = W - 10 + 1;   // 503 Sx cols (Sy has 503 rows)
constexpr int CY = W - 10;       // 502 Sy cols
constexpr int RB = 24;           // Sx rows per band
constexpr int NBANDS = (CY + RB - 1) / RB;   // 21
constexpr int NIMG = 24;
constexpr int NBLOCKS = NIMG * NBANDS;       // 504

typedef __fp16 h2 __attribute__((ext_vector_type(2)));

__device__ __forceinline__ int h2i(h2 v) { int r; __builtin_memcpy(&r, &v, 4); return r; }
__device__ __forceinline__ h2 i2h(int v) { h2 r; __builtin_memcpy(&r, &v, 4); return r; }

template <int C, int RM>
__device__ __forceinline__ int dppmov(int v) {
  return __builtin_amdgcn_update_dpp(0, v, C, RM, 0xf, true);
}
// full 64-lane inclusive prefix sum of a f16x2 pack (pure VALU)
__device__ __forceinline__ h2 scan64(h2 v) {
  v += i2h(dppmov<0x111, 0xf>(h2i(v)));  // row_shr:1
  v += i2h(dppmov<0x112, 0xf>(h2i(v)));  // row_shr:2
  v += i2h(dppmov<0x114, 0xf>(h2i(v)));  // row_shr:4
  v += i2h(dppmov<0x118, 0xf>(h2i(v)));  // row_shr:8
  v += i2h(dppmov<0x142, 0xa>(h2i(v)));  // row_bcast15 -> rows 1,3
  v += i2h(dppmov<0x143, 0xc>(h2i(v)));  // row_bcast31 -> rows 2,3
  return v;
}
__device__ __forceinline__ float wshl1(float v) {  // lane i <- lane i+1
  return __int_as_float(__builtin_amdgcn_update_dpp(0, __float_as_int(v), 0x130, 0xf, 0xf, true));
}

// LDS-only barrier: waits ds ops (lgkmcnt 0) but leaves global loads in flight.
__device__ __forceinline__ void kbarrier() {
  __builtin_amdgcn_s_waitcnt(0xC07F);   // lgkmcnt(0), vmcnt(max), expcnt(max)
  __builtin_amdgcn_s_barrier();
}

}  // namespace

// ---- per-row scan: consumes prefetch set P (A=even rows, B=odd rows), ----
// ---- produces pending window parts hY/hX/pY/pX for set P, writes bnd.  ----
#define SCANROW(S, P, TP_)                                                        \
  {                                                                               \
    constexpr int s_ = (S);                                                       \
    const int r = i0 + s_;                                                        \
    const float xl = n##P##L, xr = n##P##R, xi = n##P##I;                         \
    const float x1l = m##P##L, x1r = m##P##R, x1i = m##P##I;                      \
    if (s_ + 2 <= 33) { /* prefetch row r+2 into this set (wave-uniform) */       \
      if (r + 2 < H) {                                                            \
        n##P##L = pL[offN]; n##P##R = pR[offN]; n##P##I = pI[offN];               \
        if (lastlane) { m##P##L = pL[offN + 1]; m##P##R = pR[offN + 1]; m##P##I = pI[offN + 1]; } \
        offN += W;                                                                \
      }                                                                           \
    }                                                                             \
    float nxl = wshl1(xl), nxr = wshl1(xr), nxi = wshl1(xi);                      \
    if (lastlane) { nxl = x1l; nxr = x1r; nxi = x1i; }                            \
    const float gyl = nxl - xl, gyr = nxr - xr, gyi = nxi - xi;                   \
    const float gxl = xl - prevL, gxr = xr - prevR, gxi = xi - prevI;             \
    prevL = xl; prevR = xr; prevI = xi;                                           \
    if (r < gyEnd && j < W - 1) accGY += fabsf(gyl + gyr - gyi);                  \
    if (s_ > 0 && (r - 1) < gxEnd) accGX += fabsf(gxl + gxr - gxi);               \
    float yn = fabsf(gyl) + fabsf(gyr), yd = fabsf(gyi);                          \
    float xn = fabsf(gxl) + fabsf(gxr), xd = fabsf(gxi);                          \
    if (j == W - 1) { yn = 0.f; yd = 0.f; }                                       \
    if (r >= H) { yn = 0.f; yd = 0.f; xn = 0.f; xd = 0.f; }                       \
    const h2 Y = __builtin_amdgcn_cvt_pkrtz(yn, yd);                              \
    h2 X = (h2)(__fp16)0;                                                         \
    if (s_ != 0) X = __builtin_amdgcn_cvt_pkrtz(xn, xd);                          \
    const h2 AY = scan64(Y), AX = scan64(X);                                      \
    const h2 eY = i2h(dppmov<0x138, 0xf>(h2i(AY)));  /* A[lane-1], wave_shr:1 */  \
    const h2 eX = i2h(dppmov<0x138, 0xf>(h2i(AX)));                               \
    const h2 TY = i2h(__builtin_amdgcn_readlane(h2i(AY), 63));                    \
    const h2 TX = i2h(__builtin_amdgcn_readlane(h2i(AX), 63));                    \
    hY##P = i2h(__shfl(h2i(AY), lane9)) - eY;        /* A[lane+9]-A[lane-1] */    \
    hX##P = i2h(__shfl(h2i(AX), lane9)) - eX;                                     \
    pY##P = TY - eY; pX##P = TX - eX;                                             \
    if (lane <= 8) bndArr[TP_][s_ & 1][wv][lane] = make_int2(h2i(AY), h2i(AX));   \
  }

// ---- deferred patch + vertical ring update for row TT (set P), one      ----
// ---- superstep after its SCANROW; bnd/hist reads were issued at phase top ---
#define PATCHRING(TT, P, SNAP)                                                    \
  {                                                                               \
    constexpr int t_ = (TT);                                                      \
    h2 hY = ohY##P, hX = ohX##P;                                                  \
    if (patch) { /* lanes 55..63: window spills into next wave */                 \
      hY = i2h(bndRd##P.x) + opY##P;                                              \
      hX = i2h(bndRd##P.y) + opX##P;                                              \
    }                                                                             \
    runY += hY - i2h(histRd##P.x);                                                \
    runX += hX - i2h(histRd##P.y);                                                \
    histLds[(t_ + 20) % 10][j] = make_int2(h2i(hY), h2i(hX));                     \
    SNAP = runX; /* = Sx row t_-10 */                                             \
    if (t_ >= 9) {                                                                \
      const int iY = (i0 + t_) - 9;                                               \
      if (iY <= sxEnd && j < CY) syring[iY & 7][j] = h2i(runY);                   \
    }                                                                             \
  }

// ---- post-barrier ratio for Sx row U; Sy rows U,U+1 are >=1 phase old ----
#define RATIO(U, SNAP)                                                            \
  {                                                                               \
    constexpr int u_ = (U);                                                       \
    if (u_ >= 0) {                                                                \
      const int iX = i0 + u_;                                                     \
      if (iX < sxEnd && j < CX) {                                                 \
        int jy = iX + j, rw = iX;                                                 \
        if (jy >= CY) { jy -= CY; ++rw; }                                         \
        const h2 sy = i2h(syring[rw & 7][jy]);                                    \
        const float num = (float)SNAP.x + (float)sy.x;                            \
        const float den = (float)SNAP.y + (float)sy.y + 1e-4f;                    \
        accN += num * __builtin_amdgcn_rcpf(den);                                 \
      }                                                                           \
    }                                                                             \
  }

// ---- 2-row superstep: reads first, 4 scan chains, deferred patch/ring, ----
// ---- ONE lgkm barrier, post-barrier ratios.                             ----
#define SUPER(T_)                                                                 \
  {                                                                               \
    constexpr int tT = (T_);                                                      \
    constexpr int TP = tT & 1;                                                    \
    constexpr int a0 = 2 * tT, a1 = a0 + 1;                                       \
    int2 histRdA = make_int2(0, 0), histRdB = make_int2(0, 0);                    \
    int2 bndRdA = make_int2(0, 0), bndRdB = make_int2(0, 0);                      \
    h2 ohYA = hYA, ohXA = hXA, opYA = pYA, opXA = pXA;                            \
    h2 ohYB = hYB, ohXB = hXB, opYB = pYB, opXB = pXB;                            \
    if (tT >= 1) { /* issue ds reads early; consumed after the scans */           \
      histRdA = histLds[(a0 - 2 + 20) % 10][j];                                   \
      histRdB = histLds[(a0 - 1 + 20) % 10][j];                                   \
      if (patch) {                                                                \
        bndRdA = bndArr[TP ^ 1][0][wv + 1][lane - 55];                            \
        bndRdB = bndArr[TP ^ 1][1][wv + 1][lane - 55];                            \
      }                                                                           \
    }                                                                             \
    if (a0 <= 33) SCANROW(a0, A, TP);                                             \
    if (a1 <= 33) SCANROW(a1, B, TP);                                             \
    if (tT >= 1) {                                                                \
      PATCHRING(a0 - 2, A, snapA);                                                \
      PATCHRING(a0 - 1, B, snapB);                                                \
    }                                                                             \
    kbarrier();                                                                   \
    RATIO(a0 - 12, snapA);                                                        \
    RATIO(a0 - 11, snapB);                                                        \
  }

__global__ __launch_bounds__(512, 2) void ktv_main(const float* __restrict__ L,
                                                   const float* __restrict__ R,
                                                   const float* __restrict__ I,
                                                   double* __restrict__ partial) {
  const int blk = blockIdx.x;
  const int img = blk / NBANDS;
  const int band = blk % NBANDS;
  const int i0 = band * RB;
  const int j = threadIdx.x;  // column
  const int lane = j & 63;
  const int wv = j >> 6;
  const int lane9 = lane + 9;
  const bool lastlane = (lane == 63) && (j < W - 1);
  const bool patch = (lane >= 55) && (wv < 7);

  const bool lastb = (band == NBANDS - 1);
  const int gyEnd = lastb ? H : (i0 + RB);        // Gy rows owned: [i0, gyEnd)
  const int gxEnd = lastb ? (H - 1) : (i0 + RB);  // Gx rows owned: [i0, gxEnd)
  const int sxEnd = lastb ? CY : (i0 + RB);       // Sx rows owned: [i0, sxEnd)

  const size_t base = (size_t)img * (H * W);
  const float* pL = L + base;
  const float* pR = R + base;
  const float* pI = I + base;

  __shared__ int syring[8][CY];       // completed Sy rows (f16x2 n,d), depth-8 ring
  __shared__ int2 bndArr[2][2][8][9]; // [superstep parity][row parity][wave][lane0..8]
  __shared__ int2 histLds[10][512];   // 10-deep h ring per column (Y pack, X pack)
  __shared__ float redN[8], redGX[8], redGY[8];

  // zero the per-thread hist ring (thread-private slots -> no barrier needed)
#pragma unroll
  for (int t = 0; t < 10; ++t) histLds[t][j] = make_int2(0, 0);

  h2 runY = (h2)(__fp16)0, runX = (h2)(__fp16)0;
  h2 hYA = (h2)(__fp16)0, hXA = hYA, pYA = hYA, pXA = hYA;
  h2 hYB = hYA, hXB = hYA, pYB = hYA, pXB = hYA;
  h2 snapA = hYA, snapB = hYA;
  float accN = 0.f, accGX = 0.f, accGY = 0.f;
  float prevL = 0.f, prevR = 0.f, prevI = 0.f;

  // prologue: load rows i0 (set A) and i0+1 (set B), + lane-63 col j+1 patches
  int offN = i0 * W + j;
  float nAL = pL[offN], nAR = pR[offN], nAI = pI[offN];
  float mAL = 0.f, mAR = 0.f, mAI = 0.f;
  if (lastlane) { mAL = pL[offN + 1]; mAR = pR[offN + 1]; mAI = pI[offN + 1]; }
  offN += W;
  float nBL = pL[offN], nBR = pR[offN], nBI = pI[offN];
  float mBL = 0.f, mBR = 0.f, mBI = 0.f;
  if (lastlane) { mBL = pL[offN + 1]; mBR = pR[offN + 1]; mBI = pI[offN + 1]; }
  offN += W;

  // 18 supersteps cover scan rows 0..33, ring rows 0..33, ratio rows 0..23
  SUPER(0)  SUPER(1)  SUPER(2)  SUPER(3)  SUPER(4)  SUPER(5)
  SUPER(6)  SUPER(7)  SUPER(8)  SUPER(9)  SUPER(10) SUPER(11)
  SUPER(12) SUPER(13) SUPER(14) SUPER(15) SUPER(16) SUPER(17)

  // block reduction
#pragma unroll
  for (int o2 = 32; o2 > 0; o2 >>= 1) {
    accN  += __shfl_down(accN, o2);
    accGX += __shfl_down(accGX, o2);
    accGY += __shfl_down(accGY, o2);
  }
  if (lane == 0) { redN[wv] = accN; redGX[wv] = accGX; redGY[wv] = accGY; }
  __syncthreads();
  if (j == 0) {
    float n = 0.f, gx = 0.f, gy = 0.f;
#pragma unroll
    for (int w2 = 0; w2 < 8; ++w2) { n += redN[w2]; gx += redGX[w2]; gy += redGY[w2]; }
    double* p = partial + (size_t)blk * 3;
    p[0] = (double)n; p[1] = (double)gx; p[2] = (double)gy;
  }
}

__global__ __launch_bounds__(64) void ktv_reduce(const double* __restrict__ partial,
                                                 float* __restrict__ out) {
  double n = 0.0, gx = 0.0, gy = 0.0;
  for (int i = threadIdx.x; i < NBLOCKS; i += 64) {
    const double* p = partial + (size_t)i * 3;
    n += p[0]; gx += p[1]; gy += p[2];
  }
#pragma unroll
  for (int o2 = 32; o2 > 0; o2 >>= 1) {
    n  += __shfl_down(n, o2);
    gx += __shfl_down(gx, o2);
    gy += __shfl_down(gy, o2);
  }
  if (threadIdx.x == 0) {
    const double norm_loss = n / 6060144.0;          // 24*502*503
    const double grad_loss = (gx + gy) / 6279168.0;  // 24*511*512
    out[0] = (float)(1e-4 * norm_loss + grad_loss);
  }
}

extern "C" void kernel_launch(void* const* d_in, const int* in_sizes, int n_in,
                              void* d_out, int out_size, void* d_ws, size_t ws_size,
                              hipStream_t stream) {
  (void)in_sizes; (void)n_in; (void)out_size; (void)ws_size;
  const float* L = (const float*)d_in[0];
  const float* R = (const float*)d_in[1];
  const float* I = (const float*)d_in[2];
  double* partial = (double*)d_ws;   // NBLOCKS*3 doubles = 12096 B
  float* out = (float*)d_out;

  hipLaunchKernelGGL(ktv_main, dim3(NBLOCKS), dim3(512), 0, stream, L, R, I, partial);
  hipLaunchKernelGGL(ktv_reduce, dim3(1), dim3(64), 0, stream, partial, out);
}

// Round 2
// 128.556 us; speedup vs baseline: 1.0736x; 1.0563x over previous
//
#include <hip/hip_runtime.h>
#include <math.h>

// KTVLoss: inputs out_l, out_r, input_i : (8,3,512,512) fp32. Output: 1 fp32 scalar.
//
// Sx = 10x10 box sum of |dI/dh| (502x503), Sy = box sum of |dI/dw| (503x502).
// Reference pairs them by FLAT index: Sx(i,j) with Sy(i,i+j) if i+j<502 else
// Sy(i+1,i+j-502). ratio = (SxL+SyL+SxR+SyR)/(SxI+SyI+1e-4), mean over 24*502*503.
// grad part (fp32): mean|GxL+GxR-GxI| + mean|GyL+GyR-GyI| over 24*511*512 each.
// norm part carries 1e-4 weight -> packed f16 (abs err ~1e-5; validated R4-R9).
//
// R12: post-mortem of R11 showed barrier count was NOT the stall (35->19
// barriers = only -4.5%). VALU pipe demand (~2530 cyc/SIMD/superstep) matches
// the measured 36% VALUBusy of the 7040-cyc superstep => 64% is latency stall.
// This round removes the two remaining latency exposures:
//  1. Input rows now staged into an LDS ring via global_load_lds, THREE
//     supersteps ahead, with counted s_waitcnt vmcnt(12) at each barrier
//     (never 0 - loads stay in flight across barriers, T3/T4 idiom). No VMEM
//     result is ever awaited into registers.
//  2. Row values consumed as ds_read2_b32 of [j],[j+1]: kills wshl1 DPPs,
//     lastlane cndmask patches and the m* register machinery (the j+1
//     neighbor comes from LDS, race-free: staged >=3 barriers earlier).
// hist ring returns to registers (static unrolled slots); LDS budget:
// rows 8x3x513x4=49248 + syring 16064 + bnd 2304 + red 96 = 67.7 KB (<=80 KB
// => 2 blocks/CU preserved). RATIO moved to superstep TOP (lag -14/-13 rows;
// snaps read-before-update carry Sx rows 2T-14/2T-13 set at T-1; syring reads
// rows <=2T-12 vs writes >=2T-11, disjoint mod 8 => no intra-superstep race).
// All LDS reads issue at phase top, consumed ~100 instrs later.
//
// VGPR cap law (R4-R7): cap = 256/min_waves; (512,2) -> 128. Watch for spill.

namespace {

constexpr int H = 512, W = 512;
constexpr int CX = W - 10 + 1;   // 503 Sx cols (Sy has 503 rows)
constexpr int CY = W - 10;       // 502 Sy cols
constexpr int RB = 24;           // Sx rows per band
constexpr int NBANDS = (CY + RB - 1) / RB;   // 21
constexpr int NIMG = 24;
constexpr int NBLOCKS = NIMG * NBANDS;       // 504

typedef __fp16 h2 __attribute__((ext_vector_type(2)));

__device__ __forceinline__ int h2i(h2 v) { int r; __builtin_memcpy(&r, &v, 4); return r; }
__device__ __forceinline__ h2 i2h(int v) { h2 r; __builtin_memcpy(&r, &v, 4); return r; }

template <int C, int RM>
__device__ __forceinline__ int dppmov(int v) {
  return __builtin_amdgcn_update_dpp(0, v, C, RM, 0xf, true);
}
// full 64-lane inclusive prefix sum of a f16x2 pack (pure VALU)
__device__ __forceinline__ h2 scan64(h2 v) {
  v += i2h(dppmov<0x111, 0xf>(h2i(v)));  // row_shr:1
  v += i2h(dppmov<0x112, 0xf>(h2i(v)));  // row_shr:2
  v += i2h(dppmov<0x114, 0xf>(h2i(v)));  // row_shr:4
  v += i2h(dppmov<0x118, 0xf>(h2i(v)));  // row_shr:8
  v += i2h(dppmov<0x142, 0xa>(h2i(v)));  // row_bcast15 -> rows 1,3
  v += i2h(dppmov<0x143, 0xc>(h2i(v)));  // row_bcast31 -> rows 2,3
  return v;
}

// async global->LDS, 4 bytes/lane, dest = wave-uniform base + lane*4
__device__ __forceinline__ void gload(const float* g, float* l) {
  __builtin_amdgcn_global_load_lds((const __attribute__((address_space(1))) void*)g,
                                   (__attribute__((address_space(3))) void*)l, 4, 0, 0);
}

// barrier with COUNTED vmcnt: lgkmcnt(0) for LDS visibility, vmcnt(12) so the
// last two supersteps' 12 staging loads stay in flight across the barrier.
// encoding: vmcnt[3:0]=12, exp[6:4]=7(max), lgkm[11:8]=0, vmcnt[15:14]=0.
__device__ __forceinline__ void kbarrier_vm() {
  __builtin_amdgcn_sched_barrier(0);
  __builtin_amdgcn_s_waitcnt(0x007C);
  __builtin_amdgcn_s_barrier();
  __builtin_amdgcn_sched_barrier(0);
}

}  // namespace

// ---- stage row Q (clamped) of all 3 images into the LDS row ring ----
#define STAGE(Q)                                                                  \
  {                                                                               \
    constexpr int q_ = ((Q) > 33) ? 33 : (Q);                                     \
    int grow = i0 + q_;                                                           \
    if (grow > H - 1) grow = H - 1; /* last band: re-reads row 511, masked */     \
    const int goff = grow * W + j;                                                \
    gload(pL + goff, &rows[q_ & 7][0][wv * 64]);                                  \
    gload(pR + goff, &rows[q_ & 7][1][wv * 64]);                                  \
    gload(pI + goff, &rows[q_ & 7][2][wv * 64]);                                  \
  }

#define ROWRD_DECL(P)                                                             \
  float xV##P##L = 0.f, xV##P##R = 0.f, xV##P##I = 0.f;                           \
  float xN##P##L = 0.f, xN##P##R = 0.f, xN##P##I = 0.f;

// ---- read row S cols j, j+1 from the LDS ring (ds_read2_b32 pairs) ----
#define ROWRD(S, P)                                                               \
  {                                                                               \
    constexpr int sl = (S) & 7;                                                   \
    xV##P##L = rows[sl][0][j]; xN##P##L = rows[sl][0][j + 1];                     \
    xV##P##R = rows[sl][1][j]; xN##P##R = rows[sl][1][j + 1];                     \
    xV##P##I = rows[sl][2][j]; xN##P##I = rows[sl][2][j + 1];                     \
  }

// ---- per-row scan: gradients from LDS row values, DPP scans, window parts ----
#define SCANROW(S, P, TP_)                                                        \
  {                                                                               \
    constexpr int s_ = (S);                                                       \
    const int r = i0 + s_;                                                        \
    const float xl = xV##P##L, xr = xV##P##R, xi = xV##P##I;                      \
    const float gyl = xN##P##L - xl, gyr = xN##P##R - xr, gyi = xN##P##I - xi;    \
    const float gxl = xl - prevL, gxr = xr - prevR, gxi = xi - prevI;             \
    prevL = xl; prevR = xr; prevI = xi;                                           \
    if (r < gyEnd && j < W - 1) accGY += fabsf(gyl + gyr - gyi);                  \
    if (s_ > 0 && (r - 1) < gxEnd) accGX += fabsf(gxl + gxr - gxi);               \
    float yn = fabsf(gyl) + fabsf(gyr), yd = fabsf(gyi);                          \
    float xn = fabsf(gxl) + fabsf(gxr), xd = fabsf(gxi);                          \
    if (j == W - 1) { yn = 0.f; yd = 0.f; }                                       \
    if (r >= H) { yn = 0.f; yd = 0.f; xn = 0.f; xd = 0.f; }                       \
    const h2 Y = __builtin_amdgcn_cvt_pkrtz(yn, yd);                              \
    h2 X = (h2)(__fp16)0;                                                         \
    if (s_ != 0) X = __builtin_amdgcn_cvt_pkrtz(xn, xd);                          \
    const h2 AY = scan64(Y), AX = scan64(X);                                      \
    const int bpY = __shfl(h2i(AY), lane9), bpX = __shfl(h2i(AX), lane9);         \
    const h2 eY = i2h(dppmov<0x138, 0xf>(h2i(AY)));  /* A[lane-1], wave_shr:1 */  \
    const h2 eX = i2h(dppmov<0x138, 0xf>(h2i(AX)));                               \
    const h2 TY = i2h(__builtin_amdgcn_readlane(h2i(AY), 63));                    \
    const h2 TX = i2h(__builtin_amdgcn_readlane(h2i(AX), 63));                    \
    if (lane <= 8) bndArr[TP_][s_ & 1][wv][lane] = make_int2(h2i(AY), h2i(AX));   \
    hY##P = i2h(bpY) - eY;  hX##P = i2h(bpX) - eX;                                \
    pY##P = TY - eY;  pX##P = TX - eX;                                            \
  }

// ---- deferred patch + vertical ring update for row TT (set P); hist in regs ---
#define PATCHRING(TT, P)                                                          \
  {                                                                               \
    constexpr int t_ = (TT);                                                      \
    constexpr int hs = (t_ + 20) % 10;                                            \
    h2 hh = hY##P, hx = hX##P;                                                    \
    if (patch) { /* lanes 55..63: window spills into next wave */                 \
      hh = i2h(bndRd##P.x) + pY##P;                                               \
      hx = i2h(bndRd##P.y) + pX##P;                                               \
    }                                                                             \
    runY += hh - histY[hs]; histY[hs] = hh;                                       \
    runX += hx - histX[hs]; histX[hs] = hx;                                       \
    snap##P = runX;                                                               \
    if (t_ >= 9) {                                                                \
      const int iY = (i0 + t_) - 9;                                               \
      if (iY <= sxEnd && j < CY) syring[iY & 7][j] = h2i(runY);                   \
    }                                                                             \
  }

// ---- ratio for Sx row U: issue syring read at superstep top ... ----
#define RATIO_RD(U, P)                                                            \
  int syrd##P = 0, uok##P = 0;                                                    \
  {                                                                               \
    constexpr int u_ = (U);                                                       \
    if (u_ >= 0) {                                                                \
      const int iX = i0 + u_;                                                     \
      if (iX < sxEnd && j < CX) {                                                 \
        int jy = iX + j, rw = iX;                                                 \
        if (jy >= CY) { jy -= CY; ++rw; }                                         \
        syrd##P = syring[rw & 7][jy];                                             \
        uok##P = 1;                                                               \
      }                                                                           \
    }                                                                             \
  }

// ---- ... consume it (with the pre-update snap) after the row reads issue ----
#define RATIO_FIN(P)                                                              \
  if (uok##P) {                                                                   \
    const h2 sy = i2h(syrd##P);                                                   \
    const float num = (float)snap##P.x + (float)sy.x;                             \
    const float den = (float)snap##P.y + (float)sy.y + 1e-4f;                     \
    accN += num * __builtin_amdgcn_rcpf(den);                                     \
  }

// ---- 2-row superstep: all LDS reads at top, RATIO (old snaps) before PATCH, ---
// ---- scans, staging 6 rows ahead, counted-vmcnt barrier.                    ---
#define SUPER(T_)                                                                 \
  {                                                                               \
    constexpr int tT = (T_);                                                      \
    constexpr int TP = tT & 1;                                                    \
    constexpr int a0 = 2 * tT, a1 = a0 + 1;                                       \
    RATIO_RD(a0 - 14, A)                                                          \
    RATIO_RD(a0 - 13, B)                                                          \
    int2 bndRdA = make_int2(0, 0), bndRdB = make_int2(0, 0);                      \
    if (tT >= 1 && patch) {                                                       \
      bndRdA = bndArr[TP ^ 1][0][wv + 1][lane - 55];                              \
      bndRdB = bndArr[TP ^ 1][1][wv + 1][lane - 55];                              \
    }                                                                             \
    ROWRD_DECL(A) ROWRD_DECL(B)                                                   \
    if (a0 <= 33) ROWRD(a0, A)                                                    \
    RATIO_FIN(A) RATIO_FIN(B)                                                     \
    if (tT >= 1 && (a0 - 2) <= 33) PATCHRING(a0 - 2, A)                           \
    if (a1 <= 33) ROWRD(a1, B)                                                    \
    if (tT >= 1 && (a0 - 1) <= 33) PATCHRING(a0 - 1, B)                           \
    if (a0 <= 33) SCANROW(a0, A, TP)                                              \
    if (a1 <= 33) SCANROW(a1, B, TP)                                              \
    STAGE(a0 + 6) STAGE(a0 + 7)                                                   \
    kbarrier_vm();                                                                \
  }

__global__ __launch_bounds__(512, 2) void ktv_main(const float* __restrict__ L,
                                                   const float* __restrict__ R,
                                                   const float* __restrict__ I,
                                                   double* __restrict__ partial) {
  const int blk = blockIdx.x;
  const int img = blk / NBANDS;
  const int band = blk % NBANDS;
  const int i0 = band * RB;
  const int j = threadIdx.x;  // column
  const int lane = j & 63;
  const int wv = j >> 6;
  const int lane9 = lane + 9;
  const bool patch = (lane >= 55) && (wv < 7);

  const bool lastb = (band == NBANDS - 1);
  const int gyEnd = lastb ? H : (i0 + RB);        // Gy rows owned: [i0, gyEnd)
  const int gxEnd = lastb ? (H - 1) : (i0 + RB);  // Gx rows owned: [i0, gxEnd)
  const int sxEnd = lastb ? CY : (i0 + RB);       // Sx rows owned: [i0, sxEnd)

  const size_t base = (size_t)img * (H * W);
  const float* pL = L + base;
  const float* pR = R + base;
  const float* pI = I + base;

  __shared__ float rows[8][3][513];    // staged input rows, depth-8 ring (+pad col)
  __shared__ int syring[8][CY];        // completed Sy rows (f16x2 n,d), depth-8 ring
  __shared__ int2 bndArr[2][2][8][9];  // [superstep parity][row parity][wave][lane0..8]
  __shared__ float redN[8], redGX[8], redGY[8];

  h2 histY[10], histX[10];
#pragma unroll
  for (int t = 0; t < 10; ++t) { histY[t] = (h2)(__fp16)0; histX[t] = (h2)(__fp16)0; }
  h2 runY = (h2)(__fp16)0, runX = (h2)(__fp16)0;
  h2 hYA = (h2)(__fp16)0, hXA = hYA, pYA = hYA, pXA = hYA;
  h2 hYB = hYA, hXB = hYA, pYB = hYA, pXB = hYA;
  h2 snapA = hYA, snapB = hYA;
  float accN = 0.f, accGX = 0.f, accGY = 0.f;
  float prevL = 0.f, prevR = 0.f, prevI = 0.f;

  // prologue: stage rows 0..5 (18 loads); zero the j=512 pad entries
  STAGE(0) STAGE(1) STAGE(2) STAGE(3) STAGE(4) STAGE(5)
  if (j < 24) rows[j / 3][j % 3][512] = 0.f;
  __builtin_amdgcn_sched_barrier(0);
  __builtin_amdgcn_s_waitcnt(0x007C);  // vmcnt(12): rows 0,1 landed; lgkm(0)
  __builtin_amdgcn_s_barrier();
  __builtin_amdgcn_sched_barrier(0);

  // 19 supersteps: scans T=0..16 (rows 0..33), PATCH through T=17, RATIO T=7..18
  SUPER(0)  SUPER(1)  SUPER(2)  SUPER(3)  SUPER(4)  SUPER(5)
  SUPER(6)  SUPER(7)  SUPER(8)  SUPER(9)  SUPER(10) SUPER(11)
  SUPER(12) SUPER(13) SUPER(14) SUPER(15) SUPER(16) SUPER(17)
  SUPER(18)

  // block reduction
#pragma unroll
  for (int o2 = 32; o2 > 0; o2 >>= 1) {
    accN  += __shfl_down(accN, o2);
    accGX += __shfl_down(accGX, o2);
    accGY += __shfl_down(accGY, o2);
  }
  if (lane == 0) { redN[wv] = accN; redGX[wv] = accGX; redGY[wv] = accGY; }
  __syncthreads();
  if (j == 0) {
    float n = 0.f, gx = 0.f, gy = 0.f;
#pragma unroll
    for (int w2 = 0; w2 < 8; ++w2) { n += redN[w2]; gx += redGX[w2]; gy += redGY[w2]; }
    double* p = partial + (size_t)blk * 3;
    p[0] = (double)n; p[1] = (double)gx; p[2] = (double)gy;
  }
}

__global__ __launch_bounds__(64) void ktv_reduce(const double* __restrict__ partial,
                                                 float* __restrict__ out) {
  double n = 0.0, gx = 0.0, gy = 0.0;
  for (int i = threadIdx.x; i < NBLOCKS; i += 64) {
    const double* p = partial + (size_t)i * 3;
    n += p[0]; gx += p[1]; gy += p[2];
  }
#pragma unroll
  for (int o2 = 32; o2 > 0; o2 >>= 1) {
    n  += __shfl_down(n, o2);
    gx += __shfl_down(gx, o2);
    gy += __shfl_down(gy, o2);
  }
  if (threadIdx.x == 0) {
    const double norm_loss = n / 6060144.0;          // 24*502*503
    const double grad_loss = (gx + gy) / 6279168.0;  // 24*511*512
    out[0] = (float)(1e-4 * norm_loss + grad_loss);
  }
}

extern "C" void kernel_launch(void* const* d_in, const int* in_sizes, int n_in,
                              void* d_out, int out_size, void* d_ws, size_t ws_size,
                              hipStream_t stream) {
  (void)in_sizes; (void)n_in; (void)out_size; (void)ws_size;
  const float* L = (const float*)d_in[0];
  const float* R = (const float*)d_in[1];
  const float* I = (const float*)d_in[2];
  double* partial = (double*)d_ws;   // NBLOCKS*3 doubles = 12096 B
  float* out = (float*)d_out;

  hipLaunchKernelGGL(ktv_main, dim3(NBLOCKS), dim3(512), 0, stream, L, R, I, partial);
  hipLaunchKernelGGL(ktv_reduce, dim3(1), dim3(64), 0, stream, partial, out);
}

// Round 3
// 127.754 us; speedup vs baseline: 1.0803x; 1.0063x over previous
//
#include <hip/hip_runtime.h>
#include <math.h>

// KTVLoss: inputs out_l, out_r, input_i : (8,3,512,512) fp32. Output: 1 fp32 scalar.
//
// Sx = 10x10 box sum of |dI/dh| (502x503), Sy = box sum of |dI/dw| (503x502).
// Reference pairs them by FLAT index: Sx(i,j) with Sy(i,i+j) if i+j<502 else
// Sy(i+1,i+j-502). ratio = (SxL+SyL+SxR+SyR)/(SxI+SyI+1e-4), mean over 24*502*503.
// grad part (fp32): mean|GxL+GxR-GxI| + mean|GyL+GyR-GyI| over 24*511*512 each.
// norm part carries 1e-4 weight -> packed f16 (abs err ~1e-5; validated R4-R9).
//
// R13: R12 (-12%) confirmed latency-stall theory; VALUBusy 42% == VALU issue
// floor, remaining 58% = chains issued AND awaited within one superstep: the
// lane+9 ds_bpermutes + bnd patch machinery in SCANROW, drained by the
// barrier's lgkmcnt(0). This round pipelines the HORIZONTAL WINDOW through
// LDS: SCANROW only scans and ds_write_b64's the per-wave prefix pack to
// awin[superstep parity][row parity][j+1]; the NEXT superstep reads [j+10],
// [j], [64*(wv+1)] at its top and forms
//    window = P10 - P0*(lane!=0) + Tw*(lane>=55)
// (same 3 terms as scan+bnd+patch, different f16 association, <=1 ulp).
// Deletes per superstep: 4 bpermute, 4 readlane, 4 DPP, bnd array+patch
// selects, 16 VGPRs of hY/hX/pY/pX pipeline state. Every LDS read now issues
// at phase top, consumed a phase later. awin costs 16.7 KB; paid by row ring
// 8->6 (prefetch distance 6->4 rows, vmcnt(12)->vmcnt(6), still never 0).
// LDS total ~69.8 KB => 2 blocks/CU preserved.
//
// VGPR cap law (R4-R7): cap = 256/min_waves; (512,2) -> 128. Watch for spill.

namespace {

constexpr int H = 512, W = 512;
constexpr int CX = W - 10 + 1;   // 503 Sx cols (Sy has 503 rows)
constexpr int CY = W - 10;       // 502 Sy cols
constexpr int RB = 24;           // Sx rows per band
constexpr int NBANDS = (CY + RB - 1) / RB;   // 21
constexpr int NIMG = 24;
constexpr int NBLOCKS = NIMG * NBANDS;       // 504

typedef __fp16 h2 __attribute__((ext_vector_type(2)));

__device__ __forceinline__ int h2i(h2 v) { int r; __builtin_memcpy(&r, &v, 4); return r; }
__device__ __forceinline__ h2 i2h(int v) { h2 r; __builtin_memcpy(&r, &v, 4); return r; }

template <int C, int RM>
__device__ __forceinline__ int dppmov(int v) {
  return __builtin_amdgcn_update_dpp(0, v, C, RM, 0xf, true);
}
// full 64-lane inclusive prefix sum of a f16x2 pack (pure VALU)
__device__ __forceinline__ h2 scan64(h2 v) {
  v += i2h(dppmov<0x111, 0xf>(h2i(v)));  // row_shr:1
  v += i2h(dppmov<0x112, 0xf>(h2i(v)));  // row_shr:2
  v += i2h(dppmov<0x114, 0xf>(h2i(v)));  // row_shr:4
  v += i2h(dppmov<0x118, 0xf>(h2i(v)));  // row_shr:8
  v += i2h(dppmov<0x142, 0xa>(h2i(v)));  // row_bcast15 -> rows 1,3
  v += i2h(dppmov<0x143, 0xc>(h2i(v)));  // row_bcast31 -> rows 2,3
  return v;
}

// async global->LDS, 4 bytes/lane, dest = wave-uniform base + lane*4
__device__ __forceinline__ void gload(const float* g, float* l) {
  __builtin_amdgcn_global_load_lds((const __attribute__((address_space(1))) void*)g,
                                   (__attribute__((address_space(3))) void*)l, 4, 0, 0);
}

// barrier with COUNTED vmcnt(6): lgkmcnt(0) for LDS visibility; the current
// superstep's 6 staging loads stay in flight across the barrier (never 0).
// encoding: vmcnt[3:0]=6, exp[6:4]=7(max), lgkm[11:8]=0, vmcnt[15:14]=0.
__device__ __forceinline__ void kbarrier_vm() {
  __builtin_amdgcn_sched_barrier(0);
  __builtin_amdgcn_s_waitcnt(0x0076);
  __builtin_amdgcn_s_barrier();
  __builtin_amdgcn_sched_barrier(0);
}

}  // namespace

// ---- stage row Q (clamped) of all 3 images into the depth-6 LDS row ring ----
#define STAGE(Q)                                                                  \
  {                                                                               \
    constexpr int q_ = ((Q) > 33) ? 33 : (Q);                                     \
    int grow = i0 + q_;                                                           \
    if (grow > H - 1) grow = H - 1; /* last band: re-reads row 511, masked */     \
    const int goff = grow * W + j;                                                \
    gload(pL + goff, &rows[q_ % 6][0][wv * 64]);                                  \
    gload(pR + goff, &rows[q_ % 6][1][wv * 64]);                                  \
    gload(pI + goff, &rows[q_ % 6][2][wv * 64]);                                  \
  }

#define ROWRD_DECL(P)                                                             \
  float xV##P##L = 0.f, xV##P##R = 0.f, xV##P##I = 0.f;                           \
  float xN##P##L = 0.f, xN##P##R = 0.f, xN##P##I = 0.f;

// ---- read row S cols j, j+1 from the LDS ring (ds_read2_b32 pairs) ----
#define ROWRD(S, P)                                                               \
  {                                                                               \
    constexpr int sl = (S) % 6;                                                   \
    xV##P##L = rows[sl][0][j]; xN##P##L = rows[sl][0][j + 1];                     \
    xV##P##R = rows[sl][1][j]; xN##P##R = rows[sl][1][j + 1];                     \
    xV##P##I = rows[sl][2][j]; xN##P##I = rows[sl][2][j + 1];                     \
  }

// ---- per-row scan: gradients, pack, DPP scan, prefix -> awin (1 ds_write) ----
#define SCANROW(S, P, TP_)                                                        \
  {                                                                               \
    constexpr int s_ = (S);                                                       \
    const int r = i0 + s_;                                                        \
    const float xl = xV##P##L, xr = xV##P##R, xi = xV##P##I;                      \
    const float gyl = xN##P##L - xl, gyr = xN##P##R - xr, gyi = xN##P##I - xi;    \
    const float gxl = xl - prevL, gxr = xr - prevR, gxi = xi - prevI;             \
    prevL = xl; prevR = xr; prevI = xi;                                           \
    if (r < gyEnd && j < W - 1) accGY += fabsf(gyl + gyr - gyi);                  \
    if (s_ > 0 && (r - 1) < gxEnd) accGX += fabsf(gxl + gxr - gxi);               \
    float yn = fabsf(gyl) + fabsf(gyr), yd = fabsf(gyi);                          \
    float xn = fabsf(gxl) + fabsf(gxr), xd = fabsf(gxi);                          \
    if (j == W - 1) { yn = 0.f; yd = 0.f; }                                       \
    if (r >= H) { yn = 0.f; yd = 0.f; xn = 0.f; xd = 0.f; }                       \
    const h2 Y = __builtin_amdgcn_cvt_pkrtz(yn, yd);                              \
    h2 X = (h2)(__fp16)0;                                                         \
    if (s_ != 0) X = __builtin_amdgcn_cvt_pkrtz(xn, xd);                          \
    const h2 AY = scan64(Y), AX = scan64(X);                                      \
    awin[TP_][s_ & 1][j + 1] = make_int2(h2i(AY), h2i(AX));                       \
  }

// ---- window combine + vertical ring for row TT (set P); awin reads were ----
// ---- issued at superstep top, one barrier after they were written.      ----
#define PATCHRING(TT, P)                                                          \
  {                                                                               \
    constexpr int t_ = (TT);                                                      \
    constexpr int hs = (t_ + 20) % 10;                                            \
    h2 hh = i2h(w10##P.x), hx = i2h(w10##P.y);                                    \
    if (lane != 0) { hh -= i2h(w0##P.x); hx -= i2h(w0##P.y); }                    \
    if (patch) { hh += i2h(wT##P.x); hx += i2h(wT##P.y); }                        \
    runY += hh - histY[hs]; histY[hs] = hh;                                       \
    runX += hx - histX[hs]; histX[hs] = hx;                                       \
    snap##P = runX;                                                               \
    if (t_ >= 9) {                                                                \
      const int iY = (i0 + t_) - 9;                                               \
      if (iY <= sxEnd && j < CY) syring[iY & 7][j] = h2i(runY);                   \
    }                                                                             \
  }

// ---- ratio for Sx row U: issue syring read at superstep top ... ----
#define RATIO_RD(U, P)                                                            \
  int syrd##P = 0, uok##P = 0;                                                    \
  {                                                                               \
    constexpr int u_ = (U);                                                       \
    if (u_ >= 0) {                                                                \
      const int iX = i0 + u_;                                                     \
      if (iX < sxEnd && j < CX) {                                                 \
        int jy = iX + j, rw = iX;                                                 \
        if (jy >= CY) { jy -= CY; ++rw; }                                         \
        syrd##P = syring[rw & 7][jy];                                             \
        uok##P = 1;                                                               \
      }                                                                           \
    }                                                                             \
  }

// ---- ... consume it (with the previous superstep's snap) later ----
#define RATIO_FIN(P)                                                              \
  if (uok##P) {                                                                   \
    const h2 sy = i2h(syrd##P);                                                   \
    const float num = (float)snap##P.x + (float)sy.x;                             \
    const float den = (float)snap##P.y + (float)sy.y + 1e-4f;                     \
    accN += num * __builtin_amdgcn_rcpf(den);                                     \
  }

// ---- 2-row superstep: ALL LDS reads at top (syring, awin, rows), stage,  ----
// ---- then ratio / window-combine / scans, counted-vmcnt barrier.          ----
#define SUPER(T_)                                                                 \
  {                                                                               \
    constexpr int tT = (T_);                                                      \
    constexpr int TP = tT & 1;                                                    \
    constexpr int a0 = 2 * tT, a1 = a0 + 1;                                       \
    RATIO_RD(a0 - 14, A)                                                          \
    RATIO_RD(a0 - 13, B)                                                          \
    int2 w10A = make_int2(0, 0), w0A = w10A, wTA = w10A;                          \
    int2 w10B = w10A, w0B = w10A, wTB = w10A;                                     \
    if (tT >= 1) { /* prefix packs of rows a0-2, a0-1 (written last superstep) */ \
      w10A = awin[TP ^ 1][0][j + 10];                                             \
      w0A  = awin[TP ^ 1][0][j];                                                  \
      wTA  = awin[TP ^ 1][0][wtop];                                               \
      w10B = awin[TP ^ 1][1][j + 10];                                             \
      w0B  = awin[TP ^ 1][1][j];                                                  \
      wTB  = awin[TP ^ 1][1][wtop];                                               \
    }                                                                             \
    ROWRD_DECL(A) ROWRD_DECL(B)                                                   \
    if (a0 <= 33) ROWRD(a0, A)                                                    \
    if (a1 <= 33) ROWRD(a1, B)                                                    \
    STAGE(a0 + 4) STAGE(a0 + 5)                                                   \
    RATIO_FIN(A) RATIO_FIN(B)                                                     \
    if (tT >= 1 && (a0 - 2) <= 33) PATCHRING(a0 - 2, A)                           \
    if (tT >= 1 && (a0 - 1) <= 33) PATCHRING(a0 - 1, B)                           \
    if (a0 <= 33) SCANROW(a0, A, TP)                                              \
    if (a1 <= 33) SCANROW(a1, B, TP)                                              \
    kbarrier_vm();                                                                \
  }

__global__ __launch_bounds__(512, 2) void ktv_main(const float* __restrict__ L,
                                                   const float* __restrict__ R,
                                                   const float* __restrict__ I,
                                                   double* __restrict__ partial) {
  const int blk = blockIdx.x;
  const int img = blk / NBANDS;
  const int band = blk % NBANDS;
  const int i0 = band * RB;
  const int j = threadIdx.x;  // column
  const int lane = j & 63;
  const int wv = j >> 6;
  const int wtop = (wv + 1) << 6;            // awin slot holding own wave's total
  const bool patch = (lane >= 55) && (wv < 7);  // window crosses into next wave

  const bool lastb = (band == NBANDS - 1);
  const int gyEnd = lastb ? H : (i0 + RB);        // Gy rows owned: [i0, gyEnd)
  const int gxEnd = lastb ? (H - 1) : (i0 + RB);  // Gx rows owned: [i0, gxEnd)
  const int sxEnd = lastb ? CY : (i0 + RB);       // Sx rows owned: [i0, sxEnd)

  const size_t base = (size_t)img * (H * W);
  const float* pL = L + base;
  const float* pR = R + base;
  const float* pI = I + base;

  __shared__ float rows[6][3][513];    // staged input rows, depth-6 ring (+pad col)
  __shared__ int syring[8][CY];        // completed Sy rows (f16x2 n,d), depth-8 ring
  __shared__ int2 awin[2][2][522];     // prefix packs: [superstep parity][row parity]
                                       // slot k = prefix through col k-1; [64w] = T_{w-1}
  __shared__ float redN[8], redGX[8], redGY[8];

  h2 histY[10], histX[10];
#pragma unroll
  for (int t = 0; t < 10; ++t) { histY[t] = (h2)(__fp16)0; histX[t] = (h2)(__fp16)0; }
  h2 runY = (h2)(__fp16)0, runX = (h2)(__fp16)0;
  h2 snapA = (h2)(__fp16)0, snapB = snapA;
  float accN = 0.f, accGX = 0.f, accGY = 0.f;
  float prevL = 0.f, prevR = 0.f, prevI = 0.f;

  // prologue: stage rows 0..3 (12 loads); zero the j=512 pad entries
  STAGE(0) STAGE(1) STAGE(2) STAGE(3)
  if (j < 18) rows[j / 3][j % 3][512] = 0.f;
  __builtin_amdgcn_sched_barrier(0);
  __builtin_amdgcn_s_waitcnt(0x0076);  // vmcnt(6): rows 0,1 landed; lgkm(0)
  __builtin_amdgcn_s_barrier();
  __builtin_amdgcn_sched_barrier(0);

  // 19 supersteps: scans T=0..16 (rows 0..33), PATCH through T=17, RATIO T=7..18
  SUPER(0)  SUPER(1)  SUPER(2)  SUPER(3)  SUPER(4)  SUPER(5)
  SUPER(6)  SUPER(7)  SUPER(8)  SUPER(9)  SUPER(10) SUPER(11)
  SUPER(12) SUPER(13) SUPER(14) SUPER(15) SUPER(16) SUPER(17)
  SUPER(18)

  // block reduction
#pragma unroll
  for (int o2 = 32; o2 > 0; o2 >>= 1) {
    accN  += __shfl_down(accN, o2);
    accGX += __shfl_down(accGX, o2);
    accGY += __shfl_down(accGY, o2);
  }
  if (lane == 0) { redN[wv] = accN; redGX[wv] = accGX; redGY[wv] = accGY; }
  __syncthreads();
  if (j == 0) {
    float n = 0.f, gx = 0.f, gy = 0.f;
#pragma unroll
    for (int w2 = 0; w2 < 8; ++w2) { n += redN[w2]; gx += redGX[w2]; gy += redGY[w2]; }
    double* p = partial + (size_t)blk * 3;
    p[0] = (double)n; p[1] = (double)gx; p[2] = (double)gy;
  }
}

__global__ __launch_bounds__(64) void ktv_reduce(const double* __restrict__ partial,
                                                 float* __restrict__ out) {
  double n = 0.0, gx = 0.0, gy = 0.0;
  for (int i = threadIdx.x; i < NBLOCKS; i += 64) {
    const double* p = partial + (size_t)i * 3;
    n += p[0]; gx += p[1]; gy += p[2];
  }
#pragma unroll
  for (int o2 = 32; o2 > 0; o2 >>= 1) {
    n  += __shfl_down(n, o2);
    gx += __shfl_down(gx, o2);
    gy += __shfl_down(gy, o2);
  }
  if (threadIdx.x == 0) {
    const double norm_loss = n / 6060144.0;          // 24*502*503
    const double grad_loss = (gx + gy) / 6279168.0;  // 24*511*512
    out[0] = (float)(1e-4 * norm_loss + grad_loss);
  }
}

extern "C" void kernel_launch(void* const* d_in, const int* in_sizes, int n_in,
                              void* d_out, int out_size, void* d_ws, size_t ws_size,
                              hipStream_t stream) {
  (void)in_sizes; (void)n_in; (void)out_size; (void)ws_size;
  const float* L = (const float*)d_in[0];
  const float* R = (const float*)d_in[1];
  const float* I = (const float*)d_in[2];
  double* partial = (double*)d_ws;   // NBLOCKS*3 doubles = 12096 B
  float* out = (float*)d_out;

  hipLaunchKernelGGL(ktv_main, dim3(NBLOCKS), dim3(512), 0, stream, L, R, I, partial);
  hipLaunchKernelGGL(ktv_reduce, dim3(1), dim3(64), 0, stream, partial, out);
}